// Round 7
// baseline (314.584 us; speedup 1.0000x reference)
//
#include <hip/hip_runtime.h>
#include <hip/hip_bf16.h>
#include <stdint.h>
#include <stddef.h>

// BiAttentionLayer: B=8, Tc=4096, Tq=1024, D=256, fp32 in/out.
// Math: s_c (w1) cancels in softmax/U/b. exp without running max is safe
// (|S+s_q| <= ~15). b[i] = exp(m)/l.
// Round-4: d-split mm2 (wave = 64-d slice of U, P shared via LDS).
// Round-5: hybrid 2x2 mm1 split; h-reduction fused into epilogue.
// Round-6: deferred-mm2 software pipeline (P(t-1) consumed while P(t) computed).
// Round-7: registers-only mm1 A path (frag-ordered qa read straight from L2,
//          in-place prefetch of tile t+1; lgkm-only loop barrier; LDS 16 KiB).
// Round-8 FAILED: cooperative launch silently no-ops under graph capture.
// Round-9 (this round): G3 fusion kept, sync replaced by capture-safe
//   per-batch arrival counter: 64 blocks/batch do release fetch_add(cnt[b]);
//   spin-acquire until 64; then write G3 = context*h (context L1-hot, hv via
//   agent-scope atomic loads). Safe: grid = 512 = 2/CU x 256 CU co-resident
//   by __launch_bounds__(256,2) => no block waits on an undispatched block.
//   hv/cnt zeroing fused into k_qprep (memset dispatch deleted).

#define NB 8
#define TC 4096
#define TQ 1024
#define DD 256
#define JT 32
#define NJT (TQ / JT)

typedef __attribute__((ext_vector_type(4)))  float  f32x4v;
typedef __attribute__((ext_vector_type(8)))  __bf16 bf16x8v;
typedef __attribute__((ext_vector_type(4)))  __bf16 bf16x4v;

// workspace layout (bytes)
#define QA_OFF   0                              // bf16 frag-order for mm1 A: [b][it][jm][c][L][8]  (4 MiB)
#define QX_OFF   (QA_OFF + NB*NJT*16*1024)      // bf16 frag-order for mm2 B: [b][it][mt][L][8]     (4 MiB)
#define SQ_OFF   (QX_OFF + NB*NJT*16*1024)      // f32 [NB][TQ]
#define HV_OFF   (SQ_OFF + NB*TQ*4)             // f32 [NB][DD]
#define CNT_OFF  (HV_OFF + NB*DD*4)             // int [NB]

// ---------------- kernel 0: question preprocessing (+ hv/cnt zeroing) ----------------
__global__ __launch_bounds__(256) void k_qprep(const float* __restrict__ question,
                                               const float* __restrict__ w,
                                               char* __restrict__ ws) {
  uint4* qa = (uint4*)(ws + QA_OFF);
  uint4* qx = (uint4*)(ws + QX_OFF);
  float* sq = (float*)(ws + SQ_OFF);
  __shared__ __align__(16) __bf16 T[32][264];   // 528 B row stride (16-aligned)

  int bx = blockIdx.x;
  int b = bx >> 5, it = bx & 31;
  int t = threadIdx.x;

  // fused workspace init: one block per batch zeroes hv[b] and cnt[b]
  if (it == 0) {
    float* hvz = (float*)(ws + HV_OFF);
    hvz[b * DD + t] = 0.f;
    if (t == 0) *(int*)(ws + CNT_OFF + b * 4) = 0;
  }

  int j = t >> 3;         // 0..31
  int seg = t & 7;        // d segment of 32

  const float* qrow = question + ((size_t)(b * TQ + it * JT + j)) * DD + seg * 32;
  const float* w2 = w + DD;

  float part = 0.f;
#pragma unroll
  for (int k = 0; k < 8; ++k) {
    float4 v  = *(const float4*)(qrow + 4 * k);
    float4 wv = *(const float4*)(w2 + seg * 32 + 4 * k);
    part += v.x * wv.x + v.y * wv.y + v.z * wv.z + v.w * wv.w;
    bf16x4v pk = {(__bf16)v.x, (__bf16)v.y, (__bf16)v.z, (__bf16)v.w};
    *(bf16x4v*)&T[j][seg * 32 + 4 * k] = pk;
  }
  part += __shfl_xor(part, 1);
  part += __shfl_xor(part, 2);
  part += __shfl_xor(part, 4);
  if (seg == 0) sq[b * TQ + it * JT + j] = part;
  __syncthreads();

  // qa chunks: ch = (jm*8+c)*64 + L ; element T[16*jm + (L&15)][32*c + 8*(L>>4) + o]
#pragma unroll
  for (int p = 0; p < 4; ++p) {
    int ch = t + 256 * p;
    int L = ch & 63, cc = ch >> 6;
    int jm = cc >> 3, c = cc & 7;
    int nh = L & 15, qh = L >> 4;
    uint4 v = *(const uint4*)&T[16 * jm + nh][32 * c + 8 * qh];
    qa[(size_t)(b * NJT + it) * 1024 + ch] = v;
  }
  // qx chunks: ch = mt*64 + L ; element T[8*(L>>4) + o][16*mt + (L&15)]
#pragma unroll
  for (int p = 0; p < 4; ++p) {
    int ch = t + 256 * p;
    int L = ch & 63, mt = ch >> 6;
    int nh = L & 15, qh = L >> 4;
    __bf16 e[8];
#pragma unroll
    for (int o = 0; o < 8; ++o) e[o] = T[8 * qh + o][16 * mt + nh];
    qx[(size_t)(b * NJT + it) * 1024 + ch] = *(const uint4*)e;
  }
}

// ---------------- kernel 1: fused scores+softmax+U+h + ALL G chunks ----------------
// 512 blocks x 256 thr (4 waves). Block owns 64 i.
// mm1 (2x2 split): wave (wi,wj) computes S^T[16j (jm=wj)][32i (it=2wi,2wi+1)]
//   A = registers, loaded directly from L2 (frag-ordered workspace).
// mm2 (d-split, deferred): at iter t, wave wv computes
//   U[64i][64d_wv] += P(t-1) . qx(t-1)   (A = pa LDS double buffer, B = regs)
// epilogue: G0/1/2 + hv atomicAdds; per-batch counter spin; G3 = context*h.
__global__ __launch_bounds__(256, 2) void k_main(const float* __restrict__ context,
                                                 const float* __restrict__ w,
                                                 const char* __restrict__ ws,
                                                 float* __restrict__ hv,
                                                 int* __restrict__ cnt,
                                                 float* __restrict__ out) {
  const uint4*  qa = (const uint4*)(ws + QA_OFF);
  const __bf16* qx = (const __bf16*)(ws + QX_OFF);
  const float*  sq = (const float*)(ws + SQ_OFF);

  __shared__ __align__(16) __bf16 pa_lds[2][4][16][40]; // P double buffer (2 x 5 KiB)
  __shared__ __align__(16) float  sq_all[TQ];           // all s_q for this batch (4 KiB)
  __shared__ __align__(16) float  red_lm[2][4][16][2];  // [wj][it][nh][{l,m}]
  __shared__ __align__(16) float  rinv_lds[64];
  __shared__ __align__(16) float  bvv_lds[64];

  int bx = blockIdx.x;
  int b = bx & 7;                 // XCD-affine batch mapping
  int ig = bx >> 3;               // 0..63
  int t = threadIdx.x;
  int wv = t >> 6;
  int lane = t & 63;
  int wi = wv >> 1;               // i-half for mm1
  int wj = wv & 1;                // j-half for mm1
  int it0 = 2 * wi, it1 = 2 * wi + 1;
  int nh = lane & 15;             // col index (i for mm1 out, d for mm2 out)
  int qh = lane >> 4;             // quad

  const uint4* qa_b = qa + (size_t)b * NJT * 1024;
  const __bf16* qx_b = qx + (size_t)b * NJT * 8192;
  const float* sqb = sq + b * TQ;

  // this wave's A-frag base: chunk index (wj*8+c)*64 + lane
  const uint4* qa_w = qa_b + (size_t)wj * 512 + lane;

  // cw3 B-frags for i-tiles it0, it1: B[k=d][n=i] = context[i][d]*w3[d]
  bf16x8v cw3f0[8], cw3f1[8];
  {
    const float* crow0 = context + ((size_t)(b * TC + ig * 64 + 32 * wi + nh)) * DD;
    const float* crow1 = crow0 + 16 * DD;
    const float* w3 = w + 2 * DD;
#pragma unroll
    for (int c = 0; c < 8; ++c) {
      int d0 = 32 * c + 8 * qh;
      float4 g0 = *(const float4*)(w3 + d0);
      float4 g1 = *(const float4*)(w3 + d0 + 4);
      float4 f0 = *(const float4*)(crow0 + d0);
      float4 f1 = *(const float4*)(crow0 + d0 + 4);
      bf16x8v fr;
      fr[0] = (__bf16)(f0.x * g0.x); fr[1] = (__bf16)(f0.y * g0.y);
      fr[2] = (__bf16)(f0.z * g0.z); fr[3] = (__bf16)(f0.w * g0.w);
      fr[4] = (__bf16)(f1.x * g1.x); fr[5] = (__bf16)(f1.y * g1.y);
      fr[6] = (__bf16)(f1.z * g1.z); fr[7] = (__bf16)(f1.w * g1.w);
      cw3f0[c] = fr;
      float4 h0 = *(const float4*)(crow1 + d0);
      float4 h1 = *(const float4*)(crow1 + d0 + 4);
      bf16x8v hr;
      hr[0] = (__bf16)(h0.x * g0.x); hr[1] = (__bf16)(h0.y * g0.y);
      hr[2] = (__bf16)(h0.z * g0.z); hr[3] = (__bf16)(h0.w * g0.w);
      hr[4] = (__bf16)(h1.x * g1.x); hr[5] = (__bf16)(h1.y * g1.y);
      hr[6] = (__bf16)(h1.z * g1.z); hr[7] = (__bf16)(h1.w * g1.w);
      cw3f1[c] = hr;
    }
  }

  // prologue: stage s_q (4 KiB) to LDS; load A-frags for tile 0 into regs
  ((float4*)sq_all)[t] = ((const float4*)sqb)[t];

  bf16x8v afr[8];
#pragma unroll
  for (int c = 0; c < 8; ++c) afr[c] = *(const bf16x8v*)(qa_w + c * 64);

  f32x4v U[16];   // U[mi*4+nt]: rows i = mi*16+4qh+r, cols d = wv*64+nt*16+nh
#pragma unroll
  for (int k = 0; k < 16; ++k) U[k] = (f32x4v){0.f, 0.f, 0.f, 0.f};
  float m0_run = -1e30f, l0_run = 0.f;
  float m1_run = -1e30f, l1_run = 0.f;

  __syncthreads();   // sq_all visible

  // ---- peeled iteration 0: mm1 + softmax + P write (no deferred mm2 yet) ----
  {
    f32x4v S0 = {0.f, 0.f, 0.f, 0.f}, S1 = {0.f, 0.f, 0.f, 0.f};
#pragma unroll
    for (int c = 0; c < 8; ++c) {
      S0 = __builtin_amdgcn_mfma_f32_16x16x32_bf16(afr[c], cw3f0[c], S0, 0, 0, 0);
      S1 = __builtin_amdgcn_mfma_f32_16x16x32_bf16(afr[c], cw3f1[c], S1, 0, 0, 0);
    }
    // prefetch tile 1 A-frags (in-place; afr dead after mm1)
#pragma unroll
    for (int c = 0; c < 8; ++c) afr[c] = *(const bf16x8v*)(qa_w + 1024 + c * 64);

    float4 sqv = *(const float4*)&sq_all[16 * wj + 4 * qh];
    float a0 = S0[0] + sqv.x, a1 = S0[1] + sqv.y, a2 = S0[2] + sqv.z, a3 = S0[3] + sqv.w;
    float b0 = S1[0] + sqv.x, b1 = S1[1] + sqv.y, b2 = S1[2] + sqv.z, b3 = S1[3] + sqv.w;
    float e0 = __expf(a0), e1 = __expf(a1), e2 = __expf(a2), e3 = __expf(a3);
    float f0 = __expf(b0), f1 = __expf(b1), f2 = __expf(b2), f3 = __expf(b3);
    m0_run = fmaxf(m0_run, fmaxf(fmaxf(a0, a1), fmaxf(a2, a3)));
    m1_run = fmaxf(m1_run, fmaxf(fmaxf(b0, b1), fmaxf(b2, b3)));
    l0_run += (e0 + e1) + (e2 + e3);
    l1_run += (f0 + f1) + (f2 + f3);
    bf16x4v pk0 = {(__bf16)e0, (__bf16)e1, (__bf16)e2, (__bf16)e3};
    bf16x4v pk1 = {(__bf16)f0, (__bf16)f1, (__bf16)f2, (__bf16)f3};
    *(bf16x4v*)&pa_lds[0][it0][nh][16 * wj + 4 * qh] = pk0;
    *(bf16x4v*)&pa_lds[0][it1][nh][16 * wj + 4 * qh] = pk1;
    asm volatile("s_waitcnt lgkmcnt(0)\n\ts_barrier" ::: "memory");
  }

  // ---- main loop: iter t computes P(t), consumes P(t-1); lgkm-only barrier ----
  for (int itq = 1; itq < NJT; ++itq) {
    int cur = itq & 1;

    // issue B-frag loads for qx(t-1); latency hides under mm1 + pa ds_reads
    bf16x8v bqr[4];
    {
      const __bf16* qxt = qx_b + (size_t)(itq - 1) * 8192 + lane * 8;
#pragma unroll
      for (int nt = 0; nt < 4; ++nt)
        bqr[nt] = *(const bf16x8v*)(qxt + (size_t)(wv * 4 + nt) * 512);
    }

    // mm1: operands already in registers -> starts immediately post-barrier
    f32x4v S0 = {0.f, 0.f, 0.f, 0.f}, S1 = {0.f, 0.f, 0.f, 0.f};
#pragma unroll
    for (int c = 0; c < 8; ++c) {
      S0 = __builtin_amdgcn_mfma_f32_16x16x32_bf16(afr[c], cw3f0[c], S0, 0, 0, 0);
      S1 = __builtin_amdgcn_mfma_f32_16x16x32_bf16(afr[c], cw3f1[c], S1, 0, 0, 0);
    }

    // prefetch tile t+1 A-frags in-place (afr dead after mm1)
    if (itq + 1 < NJT) {
#pragma unroll
      for (int c = 0; c < 8; ++c)
        afr[c] = *(const bf16x8v*)(qa_w + (size_t)(itq + 1) * 1024 + c * 64);
    }

    // deferred mm2: U += P(t-1)[64i][32j] . qx(t-1)[32j][64d_wv]
#pragma unroll
    for (int mi = 0; mi < 4; ++mi) {
      bf16x8v af = *(const bf16x8v*)&pa_lds[cur ^ 1][mi][nh][8 * qh];
#pragma unroll
      for (int nt = 0; nt < 4; ++nt)
        U[mi * 4 + nt] = __builtin_amdgcn_mfma_f32_16x16x32_bf16(af, bqr[nt], U[mi * 4 + nt], 0, 0, 0);
    }

    // softmax for tile t
    float4 sqv = *(const float4*)&sq_all[itq * JT + 16 * wj + 4 * qh];
    float a0 = S0[0] + sqv.x, a1 = S0[1] + sqv.y, a2 = S0[2] + sqv.z, a3 = S0[3] + sqv.w;
    float b0 = S1[0] + sqv.x, b1 = S1[1] + sqv.y, b2 = S1[2] + sqv.z, b3 = S1[3] + sqv.w;
    float e0 = __expf(a0), e1 = __expf(a1), e2 = __expf(a2), e3 = __expf(a3);
    float f0 = __expf(b0), f1 = __expf(b1), f2 = __expf(b2), f3 = __expf(b3);
    m0_run = fmaxf(m0_run, fmaxf(fmaxf(a0, a1), fmaxf(a2, a3)));
    m1_run = fmaxf(m1_run, fmaxf(fmaxf(b0, b1), fmaxf(b2, b3)));
    l0_run += (e0 + e1) + (e2 + e3);
    l1_run += (f0 + f1) + (f2 + f3);

    // write P(t) to pa_lds[cur]
    bf16x4v pk0 = {(__bf16)e0, (__bf16)e1, (__bf16)e2, (__bf16)e3};
    bf16x4v pk1 = {(__bf16)f0, (__bf16)f1, (__bf16)f2, (__bf16)f3};
    *(bf16x4v*)&pa_lds[cur][it0][nh][16 * wj + 4 * qh] = pk0;
    *(bf16x4v*)&pa_lds[cur][it1][nh][16 * wj + 4 * qh] = pk1;

    asm volatile("s_waitcnt lgkmcnt(0)\n\ts_barrier" ::: "memory");
  }

  // ---- tail mm2 for tile NJT-1 ----
  {
    bf16x8v bqr[4];
    const __bf16* qxt = qx_b + (size_t)(NJT - 1) * 8192 + lane * 8;
#pragma unroll
    for (int nt = 0; nt < 4; ++nt)
      bqr[nt] = *(const bf16x8v*)(qxt + (size_t)(wv * 4 + nt) * 512);
#pragma unroll
    for (int mi = 0; mi < 4; ++mi) {
      bf16x8v af = *(const bf16x8v*)&pa_lds[(NJT - 1) & 1][mi][nh][8 * qh];
#pragma unroll
      for (int nt = 0; nt < 4; ++nt)
        U[mi * 4 + nt] = __builtin_amdgcn_mfma_f32_16x16x32_bf16(af, bqr[nt], U[mi * 4 + nt], 0, 0, 0);
    }
  }

  // quad-reduce l, m over qh (lanes with same nh): partials for this wave's
  // j-half of i-tiles it0, it1.
  float lo0 = l0_run + __shfl_xor(l0_run, 16); lo0 += __shfl_xor(lo0, 32);
  float lo1 = l1_run + __shfl_xor(l1_run, 16); lo1 += __shfl_xor(lo1, 32);
  float mo0 = fmaxf(m0_run, __shfl_xor(m0_run, 16)); mo0 = fmaxf(mo0, __shfl_xor(mo0, 32));
  float mo1 = fmaxf(m1_run, __shfl_xor(m1_run, 16)); mo1 = fmaxf(mo1, __shfl_xor(mo1, 32));
  if (lane < 16) {
    red_lm[wj][it0][nh][0] = lo0; red_lm[wj][it0][nh][1] = mo0;
    red_lm[wj][it1][nh][0] = lo1; red_lm[wj][it1][nh][1] = mo1;
  }
  __syncthreads();
  if (t < 64) {
    int it = t >> 4, n = t & 15;
    float l = red_lm[0][it][n][0] + red_lm[1][it][n][0];
    float m = fmaxf(red_lm[0][it][n][1], red_lm[1][it][n][1]);
    float ri = 1.0f / l;
    rinv_lds[t] = ri;
    bvv_lds[t] = __expf(m) * ri;    // b[i] = max(A_row) = exp(m)/l
  }
  __syncthreads();

  // epilogue part 1: G chunks 0/1/2 + h partial accumulation.
  // wave wv owns d in [wv*64, wv*64+64) for all 64 block rows.
  float hacc[4] = {0.f, 0.f, 0.f, 0.f};
#pragma unroll
  for (int mi = 0; mi < 4; ++mi) {
#pragma unroll
    for (int r = 0; r < 4; ++r) {
      int rl = mi * 16 + 4 * qh + r;
      int row = ig * 64 + rl;
      float rv = rinv_lds[rl];
      float bb = bvv_lds[rl];
      const float* crow = context + ((size_t)(b * TC + row)) * DD;
      float* orow = out + ((size_t)(b * TC + row)) * (4 * DD);
#pragma unroll
      for (int nt = 0; nt < 4; ++nt) {
        int d = wv * 64 + nt * 16 + nh;
        float c = crow[d];
        float u = U[mi * 4 + nt][r] * rv;
        orow[d] = c;
        orow[DD + d] = u;
        orow[2 * DD + d] = c * u;
        hacc[nt] += bb * c;
      }
    }
  }
  // reduce hacc over qh (4 lanes share each d), one atomic per (d) per block
#pragma unroll
  for (int nt = 0; nt < 4; ++nt) {
    float h = hacc[nt] + __shfl_xor(hacc[nt], 16);
    h += __shfl_xor(h, 32);
    if (qh == 0) atomicAdd(&hv[b * DD + wv * 64 + nt * 16 + nh], h);
  }

  // ---- per-batch arrival counter: capture-safe replacement for grid.sync ----
  // All waves' hv atomicAdds drained (vmcnt) at this barrier; then one
  // release-add signals this block's arrival.
  __syncthreads();
  if (t == 0) {
    __hip_atomic_fetch_add(&cnt[b], 1, __ATOMIC_RELEASE, __HIP_MEMORY_SCOPE_AGENT);
    // spin until all 64 blocks of batch b have arrived. Safe: grid (512
    // blocks) is fully co-resident at 2 blocks/CU x 256 CU.
    while (__hip_atomic_load(&cnt[b], __ATOMIC_ACQUIRE, __HIP_MEMORY_SCOPE_AGENT) < 64) {
      __builtin_amdgcn_s_sleep(2);
    }
  }
  __syncthreads();

  // epilogue part 2: G chunk 3 = context * h (h final). Agent-scope loads
  // for hv (cross-XCD coherent); context rows are L1/L2-hot.
  float hvv[4];
#pragma unroll
  for (int nt = 0; nt < 4; ++nt)
    hvv[nt] = __hip_atomic_load(&hv[b * DD + wv * 64 + nt * 16 + nh],
                                __ATOMIC_RELAXED, __HIP_MEMORY_SCOPE_AGENT);
#pragma unroll
  for (int mi = 0; mi < 4; ++mi) {
#pragma unroll
    for (int r = 0; r < 4; ++r) {
      int row = ig * 64 + mi * 16 + 4 * qh + r;
      const float* crow = context + ((size_t)(b * TC + row)) * DD;
      float* orow = out + ((size_t)(b * TC + row)) * (4 * DD);
#pragma unroll
      for (int nt = 0; nt < 4; ++nt) {
        int d = wv * 64 + nt * 16 + nh;
        orow[3 * DD + d] = crow[d] * hvv[nt];
      }
    }
  }
}

extern "C" void kernel_launch(void* const* d_in, const int* in_sizes, int n_in,
                              void* d_out, int out_size, void* d_ws, size_t ws_size,
                              hipStream_t stream) {
  (void)in_sizes; (void)n_in; (void)out_size; (void)ws_size;
  const float* context  = (const float*)d_in[0];
  const float* question = (const float*)d_in[1];
  const float* w        = (const float*)d_in[2];
  float* out = (float*)d_out;
  char* ws = (char*)d_ws;
  float* hv = (float*)(ws + HV_OFF);
  int* cnt = (int*)(ws + CNT_OFF);

  k_qprep<<<NB * NJT, 256, 0, stream>>>(question, w, ws);
  k_main<<<NB * (TC / 64), 256, 0, stream>>>(context, w, ws, hv, cnt, out);
}

// Round 8
// 233.908 us; speedup vs baseline: 1.3449x; 1.3449x over previous
//
#include <hip/hip_runtime.h>
#include <hip/hip_bf16.h>
#include <stdint.h>
#include <stddef.h>

// BiAttentionLayer: B=8, Tc=4096, Tq=1024, D=256, fp32 in/out.
// Math: s_c (w1) cancels in softmax/U/b. exp without running max is safe
// (|S+s_q| <= ~15). b[i] = exp(m)/l.
// Round-5: hybrid 2x2 mm1 split; h-reduction fused into epilogue.
// Round-6: deferred-mm2 software pipeline (P(t-1) consumed while P(t) computed).
// Round-7: registers-only mm1 A path; lgkm-only loop barrier; LDS 16 KiB.
// Round-9 FAILED (3x slowdown): ACQUIRE agent-scope poll = L1/L2 invalidate
//   per spin iteration on non-coherent-XCD gfx950 -> trashed L2 for blocks
//   still in the main loop.
// Round-10 (this round): fence-free arrival counter —
//   * hv atomicAdds complete at LLC (vmcnt drained by __syncthreads),
//   * arrival fetch_add RELAXED, poll RELAXED agent-scope (uncached LLC read,
//     NO cache invalidation), throttled by s_sleep(8),
//   * hv read back via RELAXED agent-scope atomic loads (uncached),
//   * k_qprep zeroes hv/cnt via relaxed agent-scope atomic stores (at LLC).
//   Co-residency: grid = 512 = 2/CU x 256 CU by __launch_bounds__(256,2).

#define NB 8
#define TC 4096
#define TQ 1024
#define DD 256
#define JT 32
#define NJT (TQ / JT)

typedef __attribute__((ext_vector_type(4)))  float  f32x4v;
typedef __attribute__((ext_vector_type(8)))  __bf16 bf16x8v;
typedef __attribute__((ext_vector_type(4)))  __bf16 bf16x4v;

// workspace layout (bytes)
#define QA_OFF   0                              // bf16 frag-order for mm1 A: [b][it][jm][c][L][8]  (4 MiB)
#define QX_OFF   (QA_OFF + NB*NJT*16*1024)      // bf16 frag-order for mm2 B: [b][it][mt][L][8]     (4 MiB)
#define SQ_OFF   (QX_OFF + NB*NJT*16*1024)      // f32 [NB][TQ]
#define HV_OFF   (SQ_OFF + NB*TQ*4)             // f32 [NB][DD]
#define CNT_OFF  (HV_OFF + NB*DD*4)             // int [NB]

// ---------------- kernel 0: question preprocessing (+ hv/cnt zeroing) ----------------
__global__ __launch_bounds__(256) void k_qprep(const float* __restrict__ question,
                                               const float* __restrict__ w,
                                               char* __restrict__ ws) {
  uint4* qa = (uint4*)(ws + QA_OFF);
  uint4* qx = (uint4*)(ws + QX_OFF);
  float* sq = (float*)(ws + SQ_OFF);
  __shared__ __align__(16) __bf16 T[32][264];   // 528 B row stride (16-aligned)

  int bx = blockIdx.x;
  int b = bx >> 5, it = bx & 31;
  int t = threadIdx.x;

  // fused workspace init: one block per batch zeroes hv[b] and cnt[b].
  // Relaxed agent-scope atomic stores land at the LLC (not dirty in one
  // XCD's L2) so k_main's uncached polls/loads see them.
  if (it == 0) {
    float* hvz = (float*)(ws + HV_OFF);
    __hip_atomic_store(&hvz[b * DD + t], 0.f, __ATOMIC_RELAXED,
                       __HIP_MEMORY_SCOPE_AGENT);
    if (t == 0) {
      int* cz = (int*)(ws + CNT_OFF);
      __hip_atomic_store(&cz[b], 0, __ATOMIC_RELAXED, __HIP_MEMORY_SCOPE_AGENT);
    }
  }

  int j = t >> 3;         // 0..31
  int seg = t & 7;        // d segment of 32

  const float* qrow = question + ((size_t)(b * TQ + it * JT + j)) * DD + seg * 32;
  const float* w2 = w + DD;

  float part = 0.f;
#pragma unroll
  for (int k = 0; k < 8; ++k) {
    float4 v  = *(const float4*)(qrow + 4 * k);
    float4 wv = *(const float4*)(w2 + seg * 32 + 4 * k);
    part += v.x * wv.x + v.y * wv.y + v.z * wv.z + v.w * wv.w;
    bf16x4v pk = {(__bf16)v.x, (__bf16)v.y, (__bf16)v.z, (__bf16)v.w};
    *(bf16x4v*)&T[j][seg * 32 + 4 * k] = pk;
  }
  part += __shfl_xor(part, 1);
  part += __shfl_xor(part, 2);
  part += __shfl_xor(part, 4);
  if (seg == 0) sq[b * TQ + it * JT + j] = part;
  __syncthreads();

  // qa chunks: ch = (jm*8+c)*64 + L ; element T[16*jm + (L&15)][32*c + 8*(L>>4) + o]
#pragma unroll
  for (int p = 0; p < 4; ++p) {
    int ch = t + 256 * p;
    int L = ch & 63, cc = ch >> 6;
    int jm = cc >> 3, c = cc & 7;
    int nh = L & 15, qh = L >> 4;
    uint4 v = *(const uint4*)&T[16 * jm + nh][32 * c + 8 * qh];
    qa[(size_t)(b * NJT + it) * 1024 + ch] = v;
  }
  // qx chunks: ch = mt*64 + L ; element T[8*(L>>4) + o][16*mt + (L&15)]
#pragma unroll
  for (int p = 0; p < 4; ++p) {
    int ch = t + 256 * p;
    int L = ch & 63, mt = ch >> 6;
    int nh = L & 15, qh = L >> 4;
    __bf16 e[8];
#pragma unroll
    for (int o = 0; o < 8; ++o) e[o] = T[8 * qh + o][16 * mt + nh];
    qx[(size_t)(b * NJT + it) * 1024 + ch] = *(const uint4*)e;
  }
}

// ---------------- kernel 1: fused scores+softmax+U+h + ALL G chunks ----------------
// 512 blocks x 256 thr (4 waves). Block owns 64 i.
// mm1 (2x2 split): wave (wi,wj) computes S^T[16j (jm=wj)][32i (it=2wi,2wi+1)]
//   A = registers, loaded directly from L2 (frag-ordered workspace).
// mm2 (d-split, deferred): at iter t, wave wv computes
//   U[64i][64d_wv] += P(t-1) . qx(t-1)   (A = pa LDS double buffer, B = regs)
// epilogue: G0/1/2 + hv atomicAdds; fence-free arrival counter; G3 = context*h.
__global__ __launch_bounds__(256, 2) void k_main(const float* __restrict__ context,
                                                 const float* __restrict__ w,
                                                 const char* __restrict__ ws,
                                                 float* __restrict__ hv,
                                                 int* __restrict__ cnt,
                                                 float* __restrict__ out) {
  const uint4*  qa = (const uint4*)(ws + QA_OFF);
  const __bf16* qx = (const __bf16*)(ws + QX_OFF);
  const float*  sq = (const float*)(ws + SQ_OFF);

  __shared__ __align__(16) __bf16 pa_lds[2][4][16][40]; // P double buffer (2 x 5 KiB)
  __shared__ __align__(16) float  sq_all[TQ];           // all s_q for this batch (4 KiB)
  __shared__ __align__(16) float  red_lm[2][4][16][2];  // [wj][it][nh][{l,m}]
  __shared__ __align__(16) float  rinv_lds[64];
  __shared__ __align__(16) float  bvv_lds[64];

  int bx = blockIdx.x;
  int b = bx & 7;                 // XCD-affine batch mapping
  int ig = bx >> 3;               // 0..63
  int t = threadIdx.x;
  int wv = t >> 6;
  int lane = t & 63;
  int wi = wv >> 1;               // i-half for mm1
  int wj = wv & 1;                // j-half for mm1
  int it0 = 2 * wi, it1 = 2 * wi + 1;
  int nh = lane & 15;             // col index (i for mm1 out, d for mm2 out)
  int qh = lane >> 4;             // quad

  const uint4* qa_b = qa + (size_t)b * NJT * 1024;
  const __bf16* qx_b = qx + (size_t)b * NJT * 8192;
  const float* sqb = sq + b * TQ;

  // this wave's A-frag base: chunk index (wj*8+c)*64 + lane
  const uint4* qa_w = qa_b + (size_t)wj * 512 + lane;

  // cw3 B-frags for i-tiles it0, it1: B[k=d][n=i] = context[i][d]*w3[d]
  bf16x8v cw3f0[8], cw3f1[8];
  {
    const float* crow0 = context + ((size_t)(b * TC + ig * 64 + 32 * wi + nh)) * DD;
    const float* crow1 = crow0 + 16 * DD;
    const float* w3 = w + 2 * DD;
#pragma unroll
    for (int c = 0; c < 8; ++c) {
      int d0 = 32 * c + 8 * qh;
      float4 g0 = *(const float4*)(w3 + d0);
      float4 g1 = *(const float4*)(w3 + d0 + 4);
      float4 f0 = *(const float4*)(crow0 + d0);
      float4 f1 = *(const float4*)(crow0 + d0 + 4);
      bf16x8v fr;
      fr[0] = (__bf16)(f0.x * g0.x); fr[1] = (__bf16)(f0.y * g0.y);
      fr[2] = (__bf16)(f0.z * g0.z); fr[3] = (__bf16)(f0.w * g0.w);
      fr[4] = (__bf16)(f1.x * g1.x); fr[5] = (__bf16)(f1.y * g1.y);
      fr[6] = (__bf16)(f1.z * g1.z); fr[7] = (__bf16)(f1.w * g1.w);
      cw3f0[c] = fr;
      float4 h0 = *(const float4*)(crow1 + d0);
      float4 h1 = *(const float4*)(crow1 + d0 + 4);
      bf16x8v hr;
      hr[0] = (__bf16)(h0.x * g0.x); hr[1] = (__bf16)(h0.y * g0.y);
      hr[2] = (__bf16)(h0.z * g0.z); hr[3] = (__bf16)(h0.w * g0.w);
      hr[4] = (__bf16)(h1.x * g1.x); hr[5] = (__bf16)(h1.y * g1.y);
      hr[6] = (__bf16)(h1.z * g1.z); hr[7] = (__bf16)(h1.w * g1.w);
      cw3f1[c] = hr;
    }
  }

  // prologue: stage s_q (4 KiB) to LDS; load A-frags for tile 0 into regs
  ((float4*)sq_all)[t] = ((const float4*)sqb)[t];

  bf16x8v afr[8];
#pragma unroll
  for (int c = 0; c < 8; ++c) afr[c] = *(const bf16x8v*)(qa_w + c * 64);

  f32x4v U[16];   // U[mi*4+nt]: rows i = mi*16+4qh+r, cols d = wv*64+nt*16+nh
#pragma unroll
  for (int k = 0; k < 16; ++k) U[k] = (f32x4v){0.f, 0.f, 0.f, 0.f};
  float m0_run = -1e30f, l0_run = 0.f;
  float m1_run = -1e30f, l1_run = 0.f;

  __syncthreads();   // sq_all visible

  // ---- peeled iteration 0: mm1 + softmax + P write (no deferred mm2 yet) ----
  {
    f32x4v S0 = {0.f, 0.f, 0.f, 0.f}, S1 = {0.f, 0.f, 0.f, 0.f};
#pragma unroll
    for (int c = 0; c < 8; ++c) {
      S0 = __builtin_amdgcn_mfma_f32_16x16x32_bf16(afr[c], cw3f0[c], S0, 0, 0, 0);
      S1 = __builtin_amdgcn_mfma_f32_16x16x32_bf16(afr[c], cw3f1[c], S1, 0, 0, 0);
    }
    // prefetch tile 1 A-frags (in-place; afr dead after mm1)
#pragma unroll
    for (int c = 0; c < 8; ++c) afr[c] = *(const bf16x8v*)(qa_w + 1024 + c * 64);

    float4 sqv = *(const float4*)&sq_all[16 * wj + 4 * qh];
    float a0 = S0[0] + sqv.x, a1 = S0[1] + sqv.y, a2 = S0[2] + sqv.z, a3 = S0[3] + sqv.w;
    float b0 = S1[0] + sqv.x, b1 = S1[1] + sqv.y, b2 = S1[2] + sqv.z, b3 = S1[3] + sqv.w;
    float e0 = __expf(a0), e1 = __expf(a1), e2 = __expf(a2), e3 = __expf(a3);
    float f0 = __expf(b0), f1 = __expf(b1), f2 = __expf(b2), f3 = __expf(b3);
    m0_run = fmaxf(m0_run, fmaxf(fmaxf(a0, a1), fmaxf(a2, a3)));
    m1_run = fmaxf(m1_run, fmaxf(fmaxf(b0, b1), fmaxf(b2, b3)));
    l0_run += (e0 + e1) + (e2 + e3);
    l1_run += (f0 + f1) + (f2 + f3);
    bf16x4v pk0 = {(__bf16)e0, (__bf16)e1, (__bf16)e2, (__bf16)e3};
    bf16x4v pk1 = {(__bf16)f0, (__bf16)f1, (__bf16)f2, (__bf16)f3};
    *(bf16x4v*)&pa_lds[0][it0][nh][16 * wj + 4 * qh] = pk0;
    *(bf16x4v*)&pa_lds[0][it1][nh][16 * wj + 4 * qh] = pk1;
    asm volatile("s_waitcnt lgkmcnt(0)\n\ts_barrier" ::: "memory");
  }

  // ---- main loop: iter t computes P(t), consumes P(t-1); lgkm-only barrier ----
  for (int itq = 1; itq < NJT; ++itq) {
    int cur = itq & 1;

    // issue B-frag loads for qx(t-1); latency hides under mm1 + pa ds_reads
    bf16x8v bqr[4];
    {
      const __bf16* qxt = qx_b + (size_t)(itq - 1) * 8192 + lane * 8;
#pragma unroll
      for (int nt = 0; nt < 4; ++nt)
        bqr[nt] = *(const bf16x8v*)(qxt + (size_t)(wv * 4 + nt) * 512);
    }

    // mm1: operands already in registers -> starts immediately post-barrier
    f32x4v S0 = {0.f, 0.f, 0.f, 0.f}, S1 = {0.f, 0.f, 0.f, 0.f};
#pragma unroll
    for (int c = 0; c < 8; ++c) {
      S0 = __builtin_amdgcn_mfma_f32_16x16x32_bf16(afr[c], cw3f0[c], S0, 0, 0, 0);
      S1 = __builtin_amdgcn_mfma_f32_16x16x32_bf16(afr[c], cw3f1[c], S1, 0, 0, 0);
    }

    // prefetch tile t+1 A-frags in-place (afr dead after mm1)
    if (itq + 1 < NJT) {
#pragma unroll
      for (int c = 0; c < 8; ++c)
        afr[c] = *(const bf16x8v*)(qa_w + (size_t)(itq + 1) * 1024 + c * 64);
    }

    // deferred mm2: U += P(t-1)[64i][32j] . qx(t-1)[32j][64d_wv]
#pragma unroll
    for (int mi = 0; mi < 4; ++mi) {
      bf16x8v af = *(const bf16x8v*)&pa_lds[cur ^ 1][mi][nh][8 * qh];
#pragma unroll
      for (int nt = 0; nt < 4; ++nt)
        U[mi * 4 + nt] = __builtin_amdgcn_mfma_f32_16x16x32_bf16(af, bqr[nt], U[mi * 4 + nt], 0, 0, 0);
    }

    // softmax for tile t
    float4 sqv = *(const float4*)&sq_all[itq * JT + 16 * wj + 4 * qh];
    float a0 = S0[0] + sqv.x, a1 = S0[1] + sqv.y, a2 = S0[2] + sqv.z, a3 = S0[3] + sqv.w;
    float b0 = S1[0] + sqv.x, b1 = S1[1] + sqv.y, b2 = S1[2] + sqv.z, b3 = S1[3] + sqv.w;
    float e0 = __expf(a0), e1 = __expf(a1), e2 = __expf(a2), e3 = __expf(a3);
    float f0 = __expf(b0), f1 = __expf(b1), f2 = __expf(b2), f3 = __expf(b3);
    m0_run = fmaxf(m0_run, fmaxf(fmaxf(a0, a1), fmaxf(a2, a3)));
    m1_run = fmaxf(m1_run, fmaxf(fmaxf(b0, b1), fmaxf(b2, b3)));
    l0_run += (e0 + e1) + (e2 + e3);
    l1_run += (f0 + f1) + (f2 + f3);

    // write P(t) to pa_lds[cur]
    bf16x4v pk0 = {(__bf16)e0, (__bf16)e1, (__bf16)e2, (__bf16)e3};
    bf16x4v pk1 = {(__bf16)f0, (__bf16)f1, (__bf16)f2, (__bf16)f3};
    *(bf16x4v*)&pa_lds[cur][it0][nh][16 * wj + 4 * qh] = pk0;
    *(bf16x4v*)&pa_lds[cur][it1][nh][16 * wj + 4 * qh] = pk1;

    asm volatile("s_waitcnt lgkmcnt(0)\n\ts_barrier" ::: "memory");
  }

  // ---- tail mm2 for tile NJT-1 ----
  {
    bf16x8v bqr[4];
    const __bf16* qxt = qx_b + (size_t)(NJT - 1) * 8192 + lane * 8;
#pragma unroll
    for (int nt = 0; nt < 4; ++nt)
      bqr[nt] = *(const bf16x8v*)(qxt + (size_t)(wv * 4 + nt) * 512);
#pragma unroll
    for (int mi = 0; mi < 4; ++mi) {
      bf16x8v af = *(const bf16x8v*)&pa_lds[(NJT - 1) & 1][mi][nh][8 * qh];
#pragma unroll
      for (int nt = 0; nt < 4; ++nt)
        U[mi * 4 + nt] = __builtin_amdgcn_mfma_f32_16x16x32_bf16(af, bqr[nt], U[mi * 4 + nt], 0, 0, 0);
    }
  }

  // quad-reduce l, m over qh (lanes with same nh): partials for this wave's
  // j-half of i-tiles it0, it1.
  float lo0 = l0_run + __shfl_xor(l0_run, 16); lo0 += __shfl_xor(lo0, 32);
  float lo1 = l1_run + __shfl_xor(l1_run, 16); lo1 += __shfl_xor(lo1, 32);
  float mo0 = fmaxf(m0_run, __shfl_xor(m0_run, 16)); mo0 = fmaxf(mo0, __shfl_xor(mo0, 32));
  float mo1 = fmaxf(m1_run, __shfl_xor(m1_run, 16)); mo1 = fmaxf(mo1, __shfl_xor(mo1, 32));
  if (lane < 16) {
    red_lm[wj][it0][nh][0] = lo0; red_lm[wj][it0][nh][1] = mo0;
    red_lm[wj][it1][nh][0] = lo1; red_lm[wj][it1][nh][1] = mo1;
  }
  __syncthreads();
  if (t < 64) {
    int it = t >> 4, n = t & 15;
    float l = red_lm[0][it][n][0] + red_lm[1][it][n][0];
    float m = fmaxf(red_lm[0][it][n][1], red_lm[1][it][n][1]);
    float ri = 1.0f / l;
    rinv_lds[t] = ri;
    bvv_lds[t] = __expf(m) * ri;    // b[i] = max(A_row) = exp(m)/l
  }
  __syncthreads();

  // epilogue part 1: G chunks 0/1/2 + h partial accumulation.
  // wave wv owns d in [wv*64, wv*64+64) for all 64 block rows.
  float hacc[4] = {0.f, 0.f, 0.f, 0.f};
#pragma unroll
  for (int mi = 0; mi < 4; ++mi) {
#pragma unroll
    for (int r = 0; r < 4; ++r) {
      int rl = mi * 16 + 4 * qh + r;
      int row = ig * 64 + rl;
      float rv = rinv_lds[rl];
      float bb = bvv_lds[rl];
      const float* crow = context + ((size_t)(b * TC + row)) * DD;
      float* orow = out + ((size_t)(b * TC + row)) * (4 * DD);
#pragma unroll
      for (int nt = 0; nt < 4; ++nt) {
        int d = wv * 64 + nt * 16 + nh;
        float c = crow[d];
        float u = U[mi * 4 + nt][r] * rv;
        orow[d] = c;
        orow[DD + d] = u;
        orow[2 * DD + d] = c * u;
        hacc[nt] += bb * c;
      }
    }
  }
  // reduce hacc over qh (4 lanes share each d), one atomic per (d) per block.
  // atomicAdd executes at the LLC (coherence point) — no fence needed.
#pragma unroll
  for (int nt = 0; nt < 4; ++nt) {
    float h = hacc[nt] + __shfl_xor(hacc[nt], 16);
    h += __shfl_xor(h, 32);
    if (qh == 0) atomicAdd(&hv[b * DD + wv * 64 + nt * 16 + nh], h);
  }

  // ---- fence-free per-batch arrival counter ----
  // __syncthreads drains vmcnt: all hv atomicAdds have completed at the LLC
  // before the arrival add. Poll is RELAXED (uncached LLC read, no cache
  // invalidation — the R9 failure mode). Co-residency guarantees progress.
  __syncthreads();
  if (t == 0) {
    __hip_atomic_fetch_add(&cnt[b], 1, __ATOMIC_RELAXED, __HIP_MEMORY_SCOPE_AGENT);
    while (__hip_atomic_load(&cnt[b], __ATOMIC_RELAXED, __HIP_MEMORY_SCOPE_AGENT) < 64) {
      __builtin_amdgcn_s_sleep(8);
    }
  }
  __syncthreads();

  // epilogue part 2: G chunk 3 = context * h (h final at LLC). Relaxed
  // agent-scope atomic loads bypass L1/L2 (read the LLC directly).
  float hvv[4];
#pragma unroll
  for (int nt = 0; nt < 4; ++nt)
    hvv[nt] = __hip_atomic_load(&hv[b * DD + wv * 64 + nt * 16 + nh],
                                __ATOMIC_RELAXED, __HIP_MEMORY_SCOPE_AGENT);
#pragma unroll
  for (int mi = 0; mi < 4; ++mi) {
#pragma unroll
    for (int r = 0; r < 4; ++r) {
      int row = ig * 64 + mi * 16 + 4 * qh + r;
      const float* crow = context + ((size_t)(b * TC + row)) * DD;
      float* orow = out + ((size_t)(b * TC + row)) * (4 * DD);
#pragma unroll
      for (int nt = 0; nt < 4; ++nt) {
        int d = wv * 64 + nt * 16 + nh;
        orow[3 * DD + d] = crow[d] * hvv[nt];
      }
    }
  }
}

extern "C" void kernel_launch(void* const* d_in, const int* in_sizes, int n_in,
                              void* d_out, int out_size, void* d_ws, size_t ws_size,
                              hipStream_t stream) {
  (void)in_sizes; (void)n_in; (void)out_size; (void)ws_size;
  const float* context  = (const float*)d_in[0];
  const float* question = (const float*)d_in[1];
  const float* w        = (const float*)d_in[2];
  float* out = (float*)d_out;
  char* ws = (char*)d_ws;
  float* hv = (float*)(ws + HV_OFF);
  int* cnt = (int*)(ws + CNT_OFF);

  k_qprep<<<NB * NJT, 256, 0, stream>>>(question, w, ws);
  k_main<<<NB * (TC / 64), 256, 0, stream>>>(context, w, ws, hv, cnt, out);
}